// Round 11
// baseline (175.288 us; speedup 1.0000x reference)
//
#include <hip/hip_runtime.h>

// Local NCC loss on (2,1,160,160,160) f32, 5x5x5 box window, SAME zero pad.
// R11: wave-autonomous, ZERO barriers. Block = 1 wave (64 thr); tile
// 32W x 8H x 8D; grid 4000 single-wave blocks (15.6 independent waves/CU —
// R5..R10 were stuck at <=18% occupancy behind per-slab __syncthreads).
// Each wave stages its own raw I/J tile (dbuf, aligned f4 writes, clean) and
// reads it with v9/v10-verified stride-2 b64 pattern; per-row W-window before
// vertical sums; v8-verified compile-time D-phase guards; outputs 2H x 2W per
// thread. Within-wave LDS ordering via compiler waits + wave_barrier fences.

#define DIM 160
#define SLAB (DIM * DIM)
#define VOL (DIM * DIM * DIM)
#define TD 8
#define ROWS 12                   // staged H rows: 8 + 4 halo
#define RST 44                    // padded row stride (floats)
#define VOFF (ROWS * RST)         // J-volume offset inside a buffer
#define NBLK 4000
#define NPART NBLK

typedef float f4 __attribute__((ext_vector_type(4), aligned(16)));
typedef float f2 __attribute__((ext_vector_type(2), aligned(8)));

// sliding 5-window sums for 2 outputs from 3 f2 (6 consecutive values)
__device__ __forceinline__ f2 hw2(const f2 r0, const f2 r1, const f2 r2) {
    const float c = (r0.y + r1.x) + r1.y;
    return (f2){(r0.x + c) + r2.x, (c + r2.x) + r2.y};
}

__global__ __launch_bounds__(64, 4) void ncc_main(const float* __restrict__ real,
                                                  const float* __restrict__ fake,
                                                  float* __restrict__ partials) {
    __shared__ __align__(16) float raw[2][2][ROWS][RST];   // 8448 B

    const int lane = threadIdx.x;

    // XCD-chunked swizzle: chunk = bid&7 (8 chunks of 500), dz fastest inside.
    const int bid = blockIdx.x;
    const int vid = (bid & 7) * 500 + (bid >> 3);
    const int dz  = vid % 20;
    const int t1  = vid / 20;          // 0..199
    const int bx  = t1 % 5;
    const int by  = (t1 / 5) % 20;
    const int nb  = t1 / 100;
    const int w0 = 32 * bx, h0 = 8 * by, d0 = TD * dz;

    const float* baseI = real + (size_t)nb * VOL;
    const float* baseJ = fake + (size_t)nb * VOL;

    // compute mapping: sc 0..15 (2-wide W strip), sr 0..3 (rows 2sr, 2sr+1)
    const int sc = lane & 15;
    const int sr = lane >> 4;
    const int co = (2 * sr) * RST + 2 * sc + 2;   // x = 2sc+2 <-> w = w0+2sc-2

    // staging: 240 tasks = 2 vols x 12 rows x 10 quads; 4 per thread
    int gof[4], lof[4];
    bool ok[4];
    const float* src[4];
#pragma unroll
    for (int k = 0; k < 4; ++k) {
        const int t   = lane + 64 * k;     // 0..255 (>=240 idle)
        const int tv  = t / 120;
        const int rem = t - 120 * tv;
        const int row = rem / 10;
        const int q   = rem - 10 * row;
        const int hg  = h0 - 2 + row;
        const int wq  = w0 - 4 + 4 * q;
        ok[k]  = (t < 240) && ((unsigned)hg < DIM) && (wq >= 0) && (wq + 3 < DIM);
        gof[k] = hg * DIM + wq;
        lof[k] = ((tv < 2 ? tv : 0) * ROWS + row) * RST + 4 * q;   // aligned f4 slot
        src[k] = (tv == 1) ? baseJ : baseI;
    }

    // zero LDS once (never-staged halo/pad slots stay zero forever)
    {
        float* L = &raw[0][0][0][0];
        for (int i = lane; i < 2 * 2 * ROWS * RST / 4; i += 64)
            *(f4*)(L + 4 * i) = (f4){0.f, 0.f, 0.f, 0.f};
    }
    __builtin_amdgcn_wave_barrier();

    // prologue: stage slab d0-2 into buf0 (d0==0 -> OOB, stays zero)
    if (d0 > 0) {
        const size_t so = (size_t)(d0 - 2) * SLAB;
        float* L = &raw[0][0][0][0];
#pragma unroll
        for (int k = 0; k < 4; ++k)
            if (ok[k]) *(f4*)(L + lof[k]) = *(const f4*)(src[k] + so + gof[k]);
    }
    __builtin_amdgcn_wave_barrier();

    const f2 z2 = (f2){0.f, 0.f};
    const f4 zf = (f4){0.f, 0.f, 0.f, 0.f};
    f2 zr0[5][5], zr1[5][5];           // [phase][quantity] per H row, static only
#pragma unroll
    for (int p = 0; p < 5; ++p)
#pragma unroll
        for (int q = 0; q < 5; ++q) { zr0[p][q] = z2; zr1[p][q] = z2; }

    f2 acc = z2;
    const float inv = 1.0f / 125.0f;
    int cur = 0;

#pragma unroll 1
    for (int a = 0; a < 3; ++a) {      // s = 5a+b, slabs 0..11
        const bool am0 = (a > 0);
#pragma unroll
        for (int b = 0; b < 5; ++b) {
            const bool compAct  = (a < 2) || (b < 2);   // s <= 11
            const bool stageAct = (a < 2) || (b == 0);  // s <= 10
            if (!compAct) continue;

            // ---- issue next-slab loads into registers (zeros if D-OOB) ----
            f4 v0 = zf, v1 = zf, v2 = zf, v3 = zf;
            if (stageAct) {
                const int dd1 = d0 - 1 + 5 * a + b;
                if ((unsigned)dd1 < DIM) {
                    const size_t so = (size_t)dd1 * SLAB;
                    if (ok[0]) v0 = *(const f4*)(src[0] + so + gof[0]);
                    if (ok[1]) v1 = *(const f4*)(src[1] + so + gof[1]);
                    if (ok[2]) v2 = *(const f4*)(src[2] + so + gof[2]);
                    if (ok[3]) v3 = *(const f4*)(src[3] + so + gof[3]);
                }
            }

            // ---- compute current slab: per-row W windows, 2 vertical sums ----
            const float* LB = &raw[cur][0][0][0];
            f2 c00 = z2, c01 = z2, c02 = z2, c03 = z2, c04 = z2;   // row 2sr
            f2 c10 = z2, c11 = z2, c12 = z2, c13 = z2, c14 = z2;   // row 2sr+1
#pragma unroll
            for (int t = 0; t < 6; ++t) {
                const float* rp = LB + co + t * RST;
                const f2 a0 = *(const f2*)(rp);
                const f2 a1 = *(const f2*)(rp + 2);
                const f2 a2 = *(const f2*)(rp + 4);
                const f2 b0 = *(const f2*)(rp + VOFF);
                const f2 b1 = *(const f2*)(rp + VOFF + 2);
                const f2 b2 = *(const f2*)(rp + VOFF + 4);
                const f2 w0v = hw2(a0, a1, a2);
                const f2 w1v = hw2(b0, b1, b2);
                const f2 w2v = hw2(a0 * a0, a1 * a1, a2 * a2);
                const f2 w3v = hw2(b0 * b0, b1 * b1, b2 * b2);
                const f2 w4v = hw2(a0 * b0, a1 * b1, a2 * b2);
                if (t < 5) { c00 += w0v; c01 += w1v; c02 += w2v; c03 += w3v; c04 += w4v; }
                if (t > 0) { c10 += w0v; c11 += w1v; c12 += w2v; c13 += w3v; c14 += w4v; }
            }

            // ---- add into active D-phases (guards uniform, indices static) ----
#pragma unroll
            for (int p = 0; p < 5; ++p) {
                const int kk  = (b - p + 5) % 5;   // compile-time
                const int bmk = b - kk;            // compile-time
                const bool doadd = (am0 || p <= b) &&
                                   (a == 0 || (a == 1 ? (bmk <= 2) : (bmk <= -3)));
                if (doadd) {
                    zr0[p][0] += c00; zr0[p][1] += c01; zr0[p][2] += c02;
                    zr0[p][3] += c03; zr0[p][4] += c04;
                    zr1[p][0] += c10; zr1[p][1] += c11; zr1[p][2] += c12;
                    zr1[p][3] += c13; zr1[p][4] += c14;
                }
            }

            // ---- completed output depth od = s-4 -> cc for 2x2 outputs ----
            const bool docomp = (a == 0) ? (b == 4) : ((a == 1) ? true : (b < 2));
            if (docomp) {
                const int pe = (b + 1) % 5;        // compile-time
                {
                    const f2 SI = zr0[pe][0], SJ = zr0[pe][1];
                    const f2 S2I = zr0[pe][2], S2J = zr0[pe][3], SIJ = zr0[pe][4];
                    const f2 t0    = SI * inv;
                    const f2 cross = SIJ - t0 * SJ;
                    const f2 iv    = S2I - t0 * SI;
                    const f2 jv    = S2J - (SJ * inv) * SJ;
                    acc += cross * cross / (iv * jv + 1e-5f);
                    zr0[pe][0] = z2; zr0[pe][1] = z2; zr0[pe][2] = z2;
                    zr0[pe][3] = z2; zr0[pe][4] = z2;
                }
                {
                    const f2 SI = zr1[pe][0], SJ = zr1[pe][1];
                    const f2 S2I = zr1[pe][2], S2J = zr1[pe][3], SIJ = zr1[pe][4];
                    const f2 t0    = SI * inv;
                    const f2 cross = SIJ - t0 * SJ;
                    const f2 iv    = S2I - t0 * SI;
                    const f2 jv    = S2J - (SJ * inv) * SJ;
                    acc += cross * cross / (iv * jv + 1e-5f);
                    zr1[pe][0] = z2; zr1[pe][1] = z2; zr1[pe][2] = z2;
                    zr1[pe][3] = z2; zr1[pe][4] = z2;
                }
            }

            __builtin_amdgcn_wave_barrier();   // reads of buf[cur] before writes below

            // ---- write staged regs into other buffer (zeros when D-OOB) ----
            if (stageAct) {
                float* LW = &raw[cur ^ 1][0][0][0];
                if (ok[0]) *(f4*)(LW + lof[0]) = v0;
                if (ok[1]) *(f4*)(LW + lof[1]) = v1;
                if (ok[2]) *(f4*)(LW + lof[2]) = v2;
                if (ok[3]) *(f4*)(LW + lof[3]) = v3;
            }
            __builtin_amdgcn_wave_barrier();   // writes before next slab's reads
            cur ^= 1;
        }
    }

    // ---- wave reduction -> one partial per wave/block ----
    float a2 = acc.x + acc.y;
#pragma unroll
    for (int off = 32; off; off >>= 1)
        a2 += __shfl_down(a2, off, 64);
    if (lane == 0)
        partials[bid] = a2;
}

__global__ void ncc_reduce(const float* __restrict__ partials, float* __restrict__ out) {
    __shared__ double ws[4];
    double s = 0.0;
    for (int i = threadIdx.x; i < NPART; i += 256) s += (double)partials[i];
#pragma unroll
    for (int off = 32; off; off >>= 1)
        s += __shfl_down(s, off, 64);
    if ((threadIdx.x & 63) == 0) ws[threadIdx.x >> 6] = s;
    __syncthreads();
    if (threadIdx.x == 0) {
        const double t = ws[0] + ws[1] + ws[2] + ws[3];
        out[0] = (float)(t / (2.0 * (double)VOL));
    }
}

extern "C" void kernel_launch(void* const* d_in, const int* in_sizes, int n_in,
                              void* d_out, int out_size, void* d_ws, size_t ws_size,
                              hipStream_t stream) {
    const float* real = (const float*)d_in[0];
    const float* fake = (const float*)d_in[1];
    float* out      = (float*)d_out;
    float* partials = (float*)d_ws;   // NPART floats

    ncc_main<<<dim3(NBLK), dim3(64), 0, stream>>>(real, fake, partials);
    ncc_reduce<<<1, 256, 0, stream>>>(partials, out);
}

// Round 12
// 59.557 us; speedup vs baseline: 2.9432x; 2.9432x over previous
//
#include <hip/hip_runtime.h>

// Local NCC loss on (2,1,160,160,160) f32, 5x5x5 box window, SAME zero pad.
// R12 = v10 compute core in 2-wave blocks (halve the sync domain, double the
// blocks/CU). Block 128 thr = 16 sc x 8 sr; tile 32W x 16H x 8D; grid 2000
// (XCD-chunked, dz fastest). LDS raw[2][2][20][44] (14.1 KB): aligned f4
// staging writes (4 tasks/thread), v9/v10-verified clean stride-2 b64 reads,
// per-row W-window before vertical sums, v8-verified compile-time D-phase
// guards, 2Hx2W outputs/thread. waves_per_eu(2,4): VGPR budget 256, min 2 -
// the v7-proven pin against the backend's spill-to-8-waves behavior (R11).

#define DIM 160
#define SLAB (DIM * DIM)
#define VOL (DIM * DIM * DIM)
#define TD 8
#define TH 16
#define ROWS 20                   // staged H rows: 16 + 4 halo
#define RST 44                    // padded row stride (floats)
#define VOFF (ROWS * RST)         // J-volume offset inside a buffer
#define NBLK 2000
#define NPART (NBLK * 2)

typedef float f4 __attribute__((ext_vector_type(4), aligned(16)));
typedef float f2 __attribute__((ext_vector_type(2), aligned(8)));

// sliding 5-window sums for 2 outputs from 3 f2 (6 consecutive values)
__device__ __forceinline__ f2 hw2(const f2 r0, const f2 r1, const f2 r2) {
    const float c = (r0.y + r1.x) + r1.y;
    return (f2){(r0.x + c) + r2.x, (c + r2.x) + r2.y};
}

__global__ __launch_bounds__(128)
__attribute__((amdgpu_waves_per_eu(2, 4)))
void ncc_main(const float* __restrict__ real,
              const float* __restrict__ fake,
              float* __restrict__ partials) {
    __shared__ __align__(16) float raw[2][2][ROWS][RST];   // 14080 B

    const int tid = threadIdx.x;

    // XCD-chunked swizzle: chunk = bid&7 (8 chunks of 250), dz fastest inside.
    const int bid = blockIdx.x;
    const int vid = (bid & 7) * 250 + (bid >> 3);
    const int dz  = vid % 20;
    const int t1  = vid / 20;          // 0..99
    const int bx  = t1 % 5;
    const int by  = (t1 / 5) % 10;
    const int nb  = t1 / 50;
    const int w0 = 32 * bx, h0 = TH * by, d0 = TD * dz;

    const float* baseI = real + (size_t)nb * VOL;
    const float* baseJ = fake + (size_t)nb * VOL;

    // compute mapping: sc 0..15 (2-wide W strip), sr 0..7 (rows 2sr, 2sr+1)
    const int sc = tid & 15;
    const int sr = tid >> 4;
    const int co = (2 * sr) * RST + 2 * sc + 2;   // x = 2sc+2 <-> w = w0+2sc-2

    // staging: 400 tasks = 2 vols x 20 rows x 10 quads; up to 4 per thread
    int gof[4], lof[4];
    bool ok[4];
    const float* src[4];
#pragma unroll
    for (int k = 0; k < 4; ++k) {
        const int t   = tid + 128 * k;
        const int tv  = (t < 400) ? (t / 200) : 0;
        const int rem = t - 200 * tv;
        const int row = (rem / 10) % ROWS;
        const int q   = rem - 10 * (rem / 10);
        const int hg  = h0 - 2 + row;
        const int wq  = w0 - 4 + 4 * q;
        ok[k]  = (t < 400) && ((unsigned)hg < DIM) && (wq >= 0) && (wq + 3 < DIM);
        gof[k] = hg * DIM + wq;
        lof[k] = (tv * ROWS + row) * RST + 4 * q;   // ALIGNED f4 slot
        src[k] = tv ? baseJ : baseI;
    }

    // zero LDS once (never-staged halo/pad slots stay zero forever)
    {
        float* L = &raw[0][0][0][0];
        for (int i = tid; i < 2 * 2 * ROWS * RST / 4; i += 128)
            *(f4*)(L + 4 * i) = (f4){0.f, 0.f, 0.f, 0.f};
    }
    __syncthreads();

    // prologue: stage slab d0-2 into buf0 (d0==0 -> OOB, stays zero)
    if (d0 > 0) {
        const size_t so = (size_t)(d0 - 2) * SLAB;
        float* L = &raw[0][0][0][0];
#pragma unroll
        for (int k = 0; k < 4; ++k)
            if (ok[k]) *(f4*)(L + lof[k]) = *(const f4*)(src[k] + so + gof[k]);
    }
    __syncthreads();

    const f2 z2 = (f2){0.f, 0.f};
    const f4 zf = (f4){0.f, 0.f, 0.f, 0.f};
    f2 zr0[5][5], zr1[5][5];           // [phase][quantity] per H row, static only
#pragma unroll
    for (int p = 0; p < 5; ++p)
#pragma unroll
        for (int q = 0; q < 5; ++q) { zr0[p][q] = z2; zr1[p][q] = z2; }

    f2 acc = z2;
    const float inv = 1.0f / 125.0f;
    int cur = 0;

#pragma unroll 1
    for (int a = 0; a < 3; ++a) {      // s = 5a+b, slabs 0..11
        const bool am0 = (a > 0);
#pragma unroll
        for (int b = 0; b < 5; ++b) {
            const bool compAct  = (a < 2) || (b < 2);   // s <= 11
            const bool stageAct = (a < 2) || (b == 0);  // s <= 10
            if (!compAct) continue;

            // ---- issue next-slab loads into registers (zeros if D-OOB) ----
            f4 v0 = zf, v1 = zf, v2 = zf, v3 = zf;
            if (stageAct) {
                const int dd1 = d0 - 1 + 5 * a + b;
                if ((unsigned)dd1 < DIM) {
                    const size_t so = (size_t)dd1 * SLAB;
                    if (ok[0]) v0 = *(const f4*)(src[0] + so + gof[0]);
                    if (ok[1]) v1 = *(const f4*)(src[1] + so + gof[1]);
                    if (ok[2]) v2 = *(const f4*)(src[2] + so + gof[2]);
                    if (ok[3]) v3 = *(const f4*)(src[3] + so + gof[3]);
                }
            }

            // ---- compute current slab: per-row W windows, 2 vertical sums ----
            const float* LB = &raw[cur][0][0][0];
            f2 c00 = z2, c01 = z2, c02 = z2, c03 = z2, c04 = z2;   // row 2sr
            f2 c10 = z2, c11 = z2, c12 = z2, c13 = z2, c14 = z2;   // row 2sr+1
#pragma unroll
            for (int t = 0; t < 6; ++t) {
                const float* rp = LB + co + t * RST;
                const f2 a0 = *(const f2*)(rp);
                const f2 a1 = *(const f2*)(rp + 2);
                const f2 a2 = *(const f2*)(rp + 4);
                const f2 b0 = *(const f2*)(rp + VOFF);
                const f2 b1 = *(const f2*)(rp + VOFF + 2);
                const f2 b2 = *(const f2*)(rp + VOFF + 4);
                const f2 w0v = hw2(a0, a1, a2);
                const f2 w1v = hw2(b0, b1, b2);
                const f2 w2v = hw2(a0 * a0, a1 * a1, a2 * a2);
                const f2 w3v = hw2(b0 * b0, b1 * b1, b2 * b2);
                const f2 w4v = hw2(a0 * b0, a1 * b1, a2 * b2);
                if (t < 5) { c00 += w0v; c01 += w1v; c02 += w2v; c03 += w3v; c04 += w4v; }
                if (t > 0) { c10 += w0v; c11 += w1v; c12 += w2v; c13 += w3v; c14 += w4v; }
            }

            // ---- add into active D-phases (guards uniform, indices static) ----
#pragma unroll
            for (int p = 0; p < 5; ++p) {
                const int kk  = (b - p + 5) % 5;   // compile-time
                const int bmk = b - kk;            // compile-time
                const bool doadd = (am0 || p <= b) &&
                                   (a == 0 || (a == 1 ? (bmk <= 2) : (bmk <= -3)));
                if (doadd) {
                    zr0[p][0] += c00; zr0[p][1] += c01; zr0[p][2] += c02;
                    zr0[p][3] += c03; zr0[p][4] += c04;
                    zr1[p][0] += c10; zr1[p][1] += c11; zr1[p][2] += c12;
                    zr1[p][3] += c13; zr1[p][4] += c14;
                }
            }

            // ---- completed output depth od = s-4 -> cc for 2x2 outputs ----
            const bool docomp = (a == 0) ? (b == 4) : ((a == 1) ? true : (b < 2));
            if (docomp) {
                const int pe = (b + 1) % 5;        // compile-time
                {
                    const f2 SI = zr0[pe][0], SJ = zr0[pe][1];
                    const f2 S2I = zr0[pe][2], S2J = zr0[pe][3], SIJ = zr0[pe][4];
                    const f2 t0    = SI * inv;
                    const f2 cross = SIJ - t0 * SJ;
                    const f2 iv    = S2I - t0 * SI;
                    const f2 jv    = S2J - (SJ * inv) * SJ;
                    acc += cross * cross / (iv * jv + 1e-5f);
                    zr0[pe][0] = z2; zr0[pe][1] = z2; zr0[pe][2] = z2;
                    zr0[pe][3] = z2; zr0[pe][4] = z2;
                }
                {
                    const f2 SI = zr1[pe][0], SJ = zr1[pe][1];
                    const f2 S2I = zr1[pe][2], S2J = zr1[pe][3], SIJ = zr1[pe][4];
                    const f2 t0    = SI * inv;
                    const f2 cross = SIJ - t0 * SJ;
                    const f2 iv    = S2I - t0 * SI;
                    const f2 jv    = S2J - (SJ * inv) * SJ;
                    acc += cross * cross / (iv * jv + 1e-5f);
                    zr1[pe][0] = z2; zr1[pe][1] = z2; zr1[pe][2] = z2;
                    zr1[pe][3] = z2; zr1[pe][4] = z2;
                }
            }

            // ---- write staged regs into other buffer (zeros when D-OOB) ----
            if (stageAct) {
                float* LW = &raw[cur ^ 1][0][0][0];
                if (ok[0]) *(f4*)(LW + lof[0]) = v0;
                if (ok[1]) *(f4*)(LW + lof[1]) = v1;
                if (ok[2]) *(f4*)(LW + lof[2]) = v2;
                if (ok[3]) *(f4*)(LW + lof[3]) = v3;
            }
            __syncthreads();
            cur ^= 1;
        }
    }

    // ---- wave reduction -> one partial per wave ----
    float a2 = acc.x + acc.y;
#pragma unroll
    for (int off = 32; off; off >>= 1)
        a2 += __shfl_down(a2, off, 64);
    if ((tid & 63) == 0)
        partials[bid * 2 + (tid >> 6)] = a2;
}

__global__ void ncc_reduce(const float* __restrict__ partials, float* __restrict__ out) {
    __shared__ double ws[4];
    double s = 0.0;
    for (int i = threadIdx.x; i < NPART; i += 256) s += (double)partials[i];
#pragma unroll
    for (int off = 32; off; off >>= 1)
        s += __shfl_down(s, off, 64);
    if ((threadIdx.x & 63) == 0) ws[threadIdx.x >> 6] = s;
    __syncthreads();
    if (threadIdx.x == 0) {
        const double t = ws[0] + ws[1] + ws[2] + ws[3];
        out[0] = (float)(t / (2.0 * (double)VOL));
    }
}

extern "C" void kernel_launch(void* const* d_in, const int* in_sizes, int n_in,
                              void* d_out, int out_size, void* d_ws, size_t ws_size,
                              hipStream_t stream) {
    const float* real = (const float*)d_in[0];
    const float* fake = (const float*)d_in[1];
    float* out      = (float*)d_out;
    float* partials = (float*)d_ws;   // NPART floats

    ncc_main<<<dim3(NBLK), dim3(128), 0, stream>>>(real, fake, partials);
    ncc_reduce<<<1, 256, 0, stream>>>(partials, out);
}